// Round 3
// baseline (920.626 us; speedup 1.0000x reference)
//
#include <hip/hip_runtime.h>

// LSTM (B=2048, T=1024, I=8, H=64) + sigmoid(FC), bf16 MFMA, software-pipelined.
//
// Each block owns 8 batch rows as TWO groups of 4. Per step:
//   interval even: MFMA_B(t)   || act_A(t)   ; barrier
//   interval odd : MFMA_A(t+1) || act_B(t)   ; barrier
// so every barrier interval has both matrix-pipe and VALU/transcendental work
// in the same wave -> mutual latency hiding. All producer->consumer edges
// cross exactly one barrier (single-buffered g/h per group is race-free).
// Grid = 256 blocks (1/CU), 4 waves. Bias enters as a constant-1.0 x-channel.
// x double-buffered in 32-step chunks; global loads issued 31 steps early.

namespace {
constexpr int T_LEN = 1024;
constexpr int TS    = 32;        // timesteps per x chunk
constexpr int XBB   = 33 * 32;   // x_lds per-batch-row stride (shorts); 33 -> 2-phase b128
constexpr int HP    = 80;        // h_lds row stride (shorts); 80 -> 2-phase b128
constexpr int GSTR  = 264;       // g_lds row stride (floats)

typedef __attribute__((ext_vector_type(8))) short  short8v;
typedef __attribute__((ext_vector_type(4))) float  float4v;
typedef unsigned short ushort_t;

__device__ __forceinline__ float fsig(float x) {
  return __builtin_amdgcn_rcpf(1.f + __expf(-x));
}
__device__ __forceinline__ float ftanh(float x) {
  return 1.f - 2.f * __builtin_amdgcn_rcpf(__expf(2.f * x) + 1.f);
}
__device__ __forceinline__ ushort_t f2bf(float f) {  // RNE
  unsigned int u = __float_as_uint(f);
  unsigned int r = ((u >> 16) & 1u) + 0x7fffu;
  return (ushort_t)((u + r) >> 16);
}

__global__ __launch_bounds__(256, 1) void lstm_pipe(
    const float* __restrict__ x,     // [B, T, 8]
    const float* __restrict__ W_ih,  // [256, 8]
    const float* __restrict__ W_hh,  // [256, 64]
    const float* __restrict__ b_ih,  // [256]
    const float* __restrict__ b_hh,  // [256]
    const float* __restrict__ fc_w,  // [64]
    const float* __restrict__ fc_b,  // [1]
    float* __restrict__ out) {       // [B]
  __shared__ __align__(16) ushort_t x_lds[2 * 8 * XBB];  // ~33 KB, 2 chunk bufs
  __shared__ __align__(16) ushort_t h_lds[2 * 4 * HP];   // 2 groups x 4 batch
  __shared__ __align__(16) float    g_lds[2 * 4 * GSTR]; // gate pre-activations
  __shared__ __align__(16) float    hf[8 * 64];          // final-step h (fp32)

  const int tid  = threadIdx.x;
  const int lane = tid & 63;
  const int wv   = tid >> 6;      // wave 0..3
  const int g4   = lane >> 4;     // MFMA k-quad
  const int nib  = lane & 15;     // MFMA m/n coord
  const int bBase = blockIdx.x * 8;

  // ---- static A fragments: tiles q = 4*wv..4*wv+3 ----
  // A[m=16q+nib][k=8*g4+j]; frag0 k=0..31 = [W_ih(8) | bias | 0...],
  // frag1 = W_hh[:,0:32], frag2 = W_hh[:,32:64].
  short8v a0[4], a1[4], a2[4];
  for (int qi = 0; qi < 4; ++qi) {
    const int n = 16 * (4 * wv + qi) + nib;
    short8v f0, f1, f2;
    for (int j = 0; j < 8; ++j) {
      const int k = 8 * g4 + j;
      float v0 = 0.f;
      if (k < 8) v0 = W_ih[n * 8 + k];
      else if (k == 8) v0 = b_ih[n] + b_hh[n];
      f0[j] = (short)f2bf(v0);
      f1[j] = (short)f2bf(W_hh[n * 64 + k]);
      f2[j] = (short)f2bf(W_hh[n * 64 + 32 + k]);
    }
    a0[qi] = f0; a1[qi] = f1; a2[qi] = f2;
  }

  // ---- LDS init: h0 = 0; x constant channels (ch8 = 1.0 bias, ch9..31 = 0) ----
  for (int i = tid; i < 2 * 4 * HP; i += 256) h_lds[i] = 0;
  for (int s = tid; s < 2 * 8 * TS; s += 256) {
    const int buf = s >> 8, rem = s & 255, bb = rem >> 5, tt = rem & 31;
    ushort_t* base = &x_lds[(buf * 8 + bb) * XBB + tt * 32];
    base[8] = 0x3f80;
    for (int ch = 9; ch < 32; ++ch) base[ch] = 0;
  }

  // ---- staging helpers: 8 floats (2 x float4) per thread per chunk ----
  float4v xr[2];
  auto stage_load = [&](int chunk) {
    const float* src = x + (size_t)bBase * (T_LEN * 8) + (size_t)chunk * (TS * 8);
#pragma unroll
    for (int i = 0; i < 2; ++i) {
      const int f = tid + 256 * i;  // float4 index 0..511
      const int bb = f >> 6, rem = f & 63;
      xr[i] = *(const float4v*)&src[(size_t)bb * (T_LEN * 8) + rem * 4];
    }
  };
  auto stage_write = [&](int buf) {
#pragma unroll
    for (int i = 0; i < 2; ++i) {
      const int f = tid + 256 * i;
      const int bb = f >> 6, rem = f & 63;
      const int tt = rem >> 1, ch4 = (rem & 1) * 4;
      union { unsigned long long u; ushort_t s[4]; } p;
      p.s[0] = f2bf(xr[i][0]); p.s[1] = f2bf(xr[i][1]);
      p.s[2] = f2bf(xr[i][2]); p.s[3] = f2bf(xr[i][3]);
      *(unsigned long long*)&x_lds[(buf * 8 + bb) * XBB + tt * 32 + ch4] = p.u;
    }
  };

  // ---- per-interval work ----
  auto do_mfma = [&](int g, int t) {
    const int buf = (t >> 5) & 1;
    const int tt = t & 31;
    const int bb = g * 4 + (nib & 3);  // nib>=4 duplicates nib&3 (broadcast)
    const short8v fx  = *(const short8v*)&x_lds[(buf * 8 + bb) * XBB + tt * 32 + 8 * g4];
    const short8v fh0 = *(const short8v*)&h_lds[(g * 4 + (nib & 3)) * HP + 8 * g4];
    const short8v fh1 = *(const short8v*)&h_lds[(g * 4 + (nib & 3)) * HP + 32 + 8 * g4];
#pragma unroll
    for (int qi = 0; qi < 4; ++qi) {
      float4v a = {0.f, 0.f, 0.f, 0.f};
      a = __builtin_amdgcn_mfma_f32_16x16x32_bf16(a0[qi], fx,  a, 0, 0, 0);
      a = __builtin_amdgcn_mfma_f32_16x16x32_bf16(a1[qi], fh0, a, 0, 0, 0);
      a = __builtin_amdgcn_mfma_f32_16x16x32_bf16(a2[qi], fh1, a, 0, 0, 0);
      // C: row(gate-in-tile)=4*g4+reg, col(batch)=nib
      if (nib < 4)
        *(float4v*)&g_lds[(g * 4 + nib) * GSTR + 16 * (4 * wv + qi) + 4 * g4] = a;
    }
  };
  auto do_act = [&](int g, int t, float& c) {
    const int b = tid >> 6, jh = tid & 63;
    const float* gr = &g_lds[(g * 4 + b) * GSTR];
    const float iv = fsig(gr[jh]);
    const float fv = fsig(gr[64 + jh]);
    const float gv = ftanh(gr[128 + jh]);
    const float ov = fsig(gr[192 + jh]);
    c = fv * c + iv * gv;
    const float h = ov * ftanh(c);
    h_lds[(g * 4 + b) * HP + jh] = f2bf(h);
    if (t == T_LEN - 1) hf[(g * 4 + b) * 64 + jh] = h;
  };

  // ---- prologue: stage chunk 0, warm pipeline with MFMA_A(0) ----
  float cA = 0.f, cB = 0.f;
  stage_load(0);
  stage_write(0);  // compiler inserts vmcnt wait before use
  __syncthreads();
  do_mfma(0, 0);
  __syncthreads();

  // ---- main pipelined loop ----
  for (int t = 0; t < T_LEN; ++t) {
    // even interval: MFMA_B(t) || act_A(t)  (+ x chunk write at chunk tail)
    do_mfma(1, t);
    do_act(0, t, cA);
    if ((t & 31) == 31 && t + 1 < T_LEN) stage_write(((t >> 5) + 1) & 1);
    __syncthreads();
    // odd interval: MFMA_A(t+1) || act_B(t)  (+ x chunk load at chunk head)
    if (t + 1 < T_LEN) do_mfma(0, t + 1);
    do_act(1, t, cB);
    if ((t & 31) == 0 && t + 32 < T_LEN) stage_load((t >> 5) + 1);
    __syncthreads();
  }

  // ---- epilogue: out[b] = sigmoid(hT . fc_w + fc_b) ----
  if (tid < 8) {
    float a = fc_b[0];
#pragma unroll
    for (int k = 0; k < 64; ++k) a += hf[tid * 64 + k] * fc_w[k];
    out[bBase + tid] = fsig(a);
  }
}
}  // namespace

extern "C" void kernel_launch(void* const* d_in, const int* in_sizes, int n_in,
                              void* d_out, int out_size, void* d_ws,
                              size_t ws_size, hipStream_t stream) {
  const float* x    = (const float*)d_in[0];
  const float* W_ih = (const float*)d_in[1];
  const float* W_hh = (const float*)d_in[2];
  const float* b_ih = (const float*)d_in[3];
  const float* b_hh = (const float*)d_in[4];
  const float* fc_w = (const float*)d_in[5];
  const float* fc_b = (const float*)d_in[6];
  float* out = (float*)d_out;

  const int B = in_sizes[0] / (T_LEN * 8);  // 2048
  lstm_pipe<<<dim3(B / 8), dim3(256), 0, stream>>>(x, W_ih, W_hh, b_ih, b_hh,
                                                   fc_w, fc_b, out);
}

// Round 4
// 630.874 us; speedup vs baseline: 1.4593x; 1.4593x over previous
//
#include <hip/hip_runtime.h>

// LSTM (B=2048, T=1024, I=8, H=64) + sigmoid(FC), bf16 MFMA,
// activations computed IN-REGISTER from MFMA accumulators.
//
// Wave wv owns gate-STRIDED M-tiles {wv, 4+wv, 8+wv, 12+wv}: acc quad g holds
// gate 64g + 16wv + 4*g4 + r for batch col nib. So for fixed (lane, r) the four
// quads are exactly (i,f,g,o) of h-index jh = 16wv+4g4+r -> the whole gate
// nonlinearity + c/h update runs on acc registers with NO LDS round trip.
// Per step: ds_read h -> 12 MFMA -> in-reg act -> ds_write h -> ONE barrier.
// h double-buffered (read buf t&1, write buf (t&1)^1) so one barrier suffices.
// R=8 rows/block, grid=256 -> 1 block/CU. N cols 8..15 duplicate rows 0..7
// (harmless; writes exec-masked to nib<8). K=96 packed [x(8)|bias(1)|0 | h(64)].

namespace {
constexpr int T_LEN = 1024;
constexpr int R     = 8;     // batch rows per block
constexpr int TS    = 32;    // timesteps of x per staged chunk
constexpr int XROW  = 264;   // x_lds row stride in shorts (132 dw = 4 mod 32)
constexpr int HP    = 72;    // h_lds row stride in shorts (36 dw = 4 mod 32)

typedef __attribute__((ext_vector_type(8))) short  short8v;
typedef __attribute__((ext_vector_type(4))) float  float4v;
typedef unsigned short u16;
typedef unsigned long long u64;

__device__ __forceinline__ float fsig(float x) {
  return __builtin_amdgcn_rcpf(1.f + __expf(-x));
}
__device__ __forceinline__ float ftanh(float x) {
  return 1.f - 2.f * __builtin_amdgcn_rcpf(__expf(2.f * x) + 1.f);
}
__device__ __forceinline__ u16 f2bf(float f) {  // RNE
  unsigned int u = __float_as_uint(f);
  unsigned int r = ((u >> 16) & 1u) + 0x7fffu;
  return (u16)((u + r) >> 16);
}

__global__ __launch_bounds__(256, 1) void lstm_reg(
    const float* __restrict__ x,     // [B, T, 8]
    const float* __restrict__ W_ih,  // [256, 8]
    const float* __restrict__ W_hh,  // [256, 64]
    const float* __restrict__ b_ih,  // [256]
    const float* __restrict__ b_hh,  // [256]
    const float* __restrict__ fc_w,  // [64]
    const float* __restrict__ fc_b,  // [1]
    float* __restrict__ out) {       // [B]
  __shared__ __align__(16) u16   x_lds[2][R][XROW];  // bf16 x, 2 chunk bufs
  __shared__ __align__(16) u16   h_lds[2][R][HP];    // bf16 h, 2 step bufs
  __shared__ __align__(16) float hf[R][64];          // final h (fp32) for FC

  const int tid  = threadIdx.x;
  const int lane = tid & 63;
  const int wv   = tid >> 6;       // wave 0..3
  const int g4   = lane >> 4;      // MFMA k-quad / C row-quad
  const int nib  = lane & 15;      // MFMA m/n coord
  const int row  = nib & 7;        // batch row (cols 8..15 duplicate 0..7)
  const int bBase = blockIdx.x * R;

  // ---- static A fragments: wave wv holds tiles {4g+wv}, g=0..3 (i,f,g,o) ----
  // A[m=16*(4g+wv)+nib][k=8*g4+j]; frag0 k=0..31 = [W_ih(8)|bias|0...],
  // frag1 = W_hh[:,0:32], frag2 = W_hh[:,32:64].
  short8v a0[4], a1[4], a2[4];
  for (int g = 0; g < 4; ++g) {
    const int n = 64 * g + 16 * wv + nib;  // gate row
    short8v f0, f1, f2;
    for (int j = 0; j < 8; ++j) {
      const int k = 8 * g4 + j;
      float v0 = 0.f;
      if (k < 8) v0 = W_ih[n * 8 + k];
      else if (k == 8) v0 = b_ih[n] + b_hh[n];
      f0[j] = (short)f2bf(v0);
      f1[j] = (short)f2bf(W_hh[n * 64 + k]);
      f2[j] = (short)f2bf(W_hh[n * 64 + 32 + k]);
    }
    a0[g] = f0; a1[g] = f1; a2[g] = f2;
  }
  short8v bias_frag = {0, 0, 0, 0, 0, 0, 0, 0};
  if (g4 == 1) bias_frag[0] = (short)0x3f80;  // B[k=8][*] = 1.0

  for (int i = tid; i < 2 * R * HP; i += 256) ((u16*)h_lds)[i] = 0;  // h0 = 0

  // ---- x staging: 8 floats/thread/chunk, double-buffered ----
  float4v xr0, xr1;
  auto stage_load = [&](int chunk) {
    const float* src = x + (size_t)bBase * (T_LEN * 8) + (size_t)chunk * (TS * 8);
    const int r0 = tid >> 6, m0 = tid & 63;
    xr0 = *(const float4v*)&src[(size_t)r0 * (T_LEN * 8) + m0 * 4];
    const int f1i = tid + 256;
    const int r1 = f1i >> 6, m1 = f1i & 63;
    xr1 = *(const float4v*)&src[(size_t)r1 * (T_LEN * 8) + m1 * 4];
  };
  auto stage_write = [&](int buf) {
    const int r0 = tid >> 6, m0 = tid & 63;
    union { u64 u; u16 s[4]; } p;
    p.s[0] = f2bf(xr0[0]); p.s[1] = f2bf(xr0[1]);
    p.s[2] = f2bf(xr0[2]); p.s[3] = f2bf(xr0[3]);
    *(u64*)&x_lds[buf][r0][m0 * 4] = p.u;
    const int f1i = tid + 256;
    const int r1 = f1i >> 6, m1 = f1i & 63;
    union { u64 u; u16 s[4]; } q;
    q.s[0] = f2bf(xr1[0]); q.s[1] = f2bf(xr1[1]);
    q.s[2] = f2bf(xr1[2]); q.s[3] = f2bf(xr1[3]);
    *(u64*)&x_lds[buf][r1][m1 * 4] = q.u;
  };

  stage_load(0);
  stage_write(0);
  __syncthreads();

  float c[4] = {0.f, 0.f, 0.f, 0.f};  // cell state: jh = 16wv+4g4+r, row nib&7

  for (int ch = 0; ch < T_LEN / TS; ++ch) {
    const int xb = ch & 1;
    const bool more = (ch < T_LEN / TS - 1);
    for (int tt = 0; tt < TS; ++tt) {
      const int t = ch * TS + tt;
      const int hb = t & 1;
      if (tt == 0 && more) stage_load(ch + 1);  // reg loads; drain at stage_write

      // ---- B fragments (the only LDS reads in the chain) ----
      short8v fx = bias_frag;
      if (g4 == 0) fx = *(const short8v*)&x_lds[xb][row][tt * 8];
      const short8v fh0 = *(const short8v*)&h_lds[hb][row][8 * g4];
      const short8v fh1 = *(const short8v*)&h_lds[hb][row][32 + 8 * g4];

      // ---- 12 MFMAs; x-part first (doesn't wait on fh) ----
      float4v acc[4];
#pragma unroll
      for (int g = 0; g < 4; ++g)
        acc[g] = __builtin_amdgcn_mfma_f32_16x16x32_bf16(
            a0[g], fx, (float4v){0.f, 0.f, 0.f, 0.f}, 0, 0, 0);
#pragma unroll
      for (int g = 0; g < 4; ++g)
        acc[g] = __builtin_amdgcn_mfma_f32_16x16x32_bf16(a1[g], fh0, acc[g], 0, 0, 0);
#pragma unroll
      for (int g = 0; g < 4; ++g)
        acc[g] = __builtin_amdgcn_mfma_f32_16x16x32_bf16(a2[g], fh1, acc[g], 0, 0, 0);

      // ---- activation fully in-register: quads = (i,f,g,o) of jh=16wv+4g4+r ----
      union { u64 u; u16 s[4]; } hp;
      float hv[4];
#pragma unroll
      for (int r = 0; r < 4; ++r) {
        const float iv = fsig(acc[0][r]);
        const float fv = fsig(acc[1][r]);
        const float gv = ftanh(acc[2][r]);
        const float ov = fsig(acc[3][r]);
        c[r] = fv * c[r] + iv * gv;
        hv[r] = ov * ftanh(c[r]);
        hp.s[r] = f2bf(hv[r]);
      }
      if (nib < 8) *(u64*)&h_lds[hb ^ 1][row][16 * wv + 4 * g4] = hp.u;
      if (t == T_LEN - 1 && nib < 8) {
#pragma unroll
        for (int r = 0; r < 4; ++r) hf[row][16 * wv + 4 * g4 + r] = hv[r];
      }
      if (tt == TS - 1 && more) stage_write((ch + 1) & 1);
      __syncthreads();  // the ONE barrier per step
    }
  }

  // ---- epilogue: out[b] = sigmoid(hT . fc_w + fc_b) ----
  if (tid < R) {
    float a = fc_b[0];
#pragma unroll
    for (int k = 0; k < 64; ++k) a += hf[tid][k] * fc_w[k];
    out[bBase + tid] = fsig(a);
  }
}
}  // namespace

extern "C" void kernel_launch(void* const* d_in, const int* in_sizes, int n_in,
                              void* d_out, int out_size, void* d_ws,
                              size_t ws_size, hipStream_t stream) {
  const float* x    = (const float*)d_in[0];
  const float* W_ih = (const float*)d_in[1];
  const float* W_hh = (const float*)d_in[2];
  const float* b_ih = (const float*)d_in[3];
  const float* b_hh = (const float*)d_in[4];
  const float* fc_w = (const float*)d_in[5];
  const float* fc_b = (const float*)d_in[6];
  float* out = (float*)d_out;

  const int B = in_sizes[0] / (T_LEN * 8);  // 2048
  lstm_reg<<<dim3(B / R), dim3(256), 0, stream>>>(x, W_ih, W_hh, b_ih, b_hh,
                                                  fc_w, fc_b, out);
}

// Round 5
// 488.094 us; speedup vs baseline: 1.8862x; 1.2925x over previous
//
#include <hip/hip_runtime.h>

// LSTM (B=2048, T=1024, I=8, H=64) + sigmoid(FC), bf16 MFMA, in-register
// activations, duplicate-column split, 2 blocks/CU.
//
// R=4 batch rows/block -> 512 blocks = 2/CU (launch_bounds(256,2)); the two
// co-resident blocks cover each other's barrier + latency shadows.
// MFMA N-columns: col nib carries batch row nib&3 (4 duplicate groups).
// Wave wv owns gate-strided M-tiles {4g+wv}: acc[g][r] = gate quarter g of
// h-index jh = 16wv+4g4+r, col nib. Thread activates ONE element, picking
// r = rsel = nib>>2 from its acc regs via a hoisted cndmask tree -> activation
// issue (10 quarter-rate transcendentals) drops 4x vs round 4.
// x is staged as full 32-wide K-rows [tt][row][32] with ch8=1.0 (bias) and
// ch9..31=0 prefilled once -> fx is one uniform ds_read_b128, no select.
// Per step: 3 ds_read_b128 -> 12 MFMA -> 1-elem act -> ds_write_b16 -> barrier.

namespace {
constexpr int T_LEN = 1024;
constexpr int R     = 4;    // batch rows per block
constexpr int TS    = 32;   // timesteps of x per staged chunk
constexpr int HP    = 40;   // h_lds row stride in shorts (80 B, 16B-aligned)

typedef __attribute__((ext_vector_type(8))) short  short8v;
typedef __attribute__((ext_vector_type(4))) float  float4v;
typedef unsigned short u16;
typedef unsigned long long u64;

__device__ __forceinline__ float fsig(float x) {
  return __builtin_amdgcn_rcpf(1.f + __expf(-x));
}
__device__ __forceinline__ float ftanh(float x) {
  return 1.f - 2.f * __builtin_amdgcn_rcpf(__expf(2.f * x) + 1.f);
}
__device__ __forceinline__ u16 f2bf(float f) {  // RNE
  unsigned int u = __float_as_uint(f);
  unsigned int r = ((u >> 16) & 1u) + 0x7fffu;
  return (u16)((u + r) >> 16);
}

__global__ __launch_bounds__(256, 2) void lstm_split(
    const float* __restrict__ x,     // [B, T, 8]
    const float* __restrict__ W_ih,  // [256, 8]
    const float* __restrict__ W_hh,  // [256, 64]
    const float* __restrict__ b_ih,  // [256]
    const float* __restrict__ b_hh,  // [256]
    const float* __restrict__ fc_w,  // [64]
    const float* __restrict__ fc_b,  // [1]
    float* __restrict__ out) {       // [B]
  __shared__ __align__(16) u16   x_lds[2][TS][R][32];  // 16 KB; full K-rows
  __shared__ __align__(16) u16   h_lds[2][R][HP];      // 640 B
  __shared__ __align__(16) float hf[R][64];            // final h (fp32)

  const int tid  = threadIdx.x;
  const int lane = tid & 63;
  const int wv   = tid >> 6;       // wave 0..3
  const int g4   = lane >> 4;      // MFMA k-quad / C row-quad
  const int nib  = lane & 15;      // MFMA m/n coord
  const int row  = nib & 3;        // batch row (cols 4..15 duplicate 0..3)
  const int rsel = nib >> 2;       // which acc reg this thread activates
  const int jh   = 16 * wv + 4 * g4 + rsel;  // owned h index
  const int bBase = blockIdx.x * R;

  // ---- static A fragments: wave wv holds tiles {4g+wv}, g=0..3 (i,f,g,o) ----
  // A[m=16*(4g+wv)+nib][k=8*g4+j]; frag0 k=0..31 = [W_ih(8)|bias|0...],
  // frag1 = W_hh[:,0:32], frag2 = W_hh[:,32:64].
  short8v a0[4], a1[4], a2[4];
  for (int g = 0; g < 4; ++g) {
    const int n = 64 * g + 16 * wv + nib;  // gate row
    short8v f0, f1, f2;
    for (int j = 0; j < 8; ++j) {
      const int k = 8 * g4 + j;
      float v0 = 0.f;
      if (k < 8) v0 = W_ih[n * 8 + k];
      else if (k == 8) v0 = b_ih[n] + b_hh[n];
      f0[j] = (short)f2bf(v0);
      f1[j] = (short)f2bf(W_hh[n * 64 + k]);
      f2[j] = (short)f2bf(W_hh[n * 64 + 32 + k]);
    }
    a0[g] = f0; a1[g] = f1; a2[g] = f2;
  }

  // ---- LDS init: h0 = 0 (both bufs); x constant channels once per buf ----
  for (int i = tid; i < 2 * R * HP; i += 256) ((u16*)h_lds)[i] = 0;
  {  // 256 threads <-> 2 bufs x 32 tt x 4 rows
    const int buf = tid >> 7, rem = tid & 127, tt = rem >> 2, rr = rem & 3;
    u16* p = &x_lds[buf][tt][rr][0];
    p[8] = 0x3f80;  // bias channel = 1.0
    for (int ch = 9; ch < 32; ++ch) p[ch] = 0;
  }

  // ---- x staging: 1 float4/thread/chunk, double-buffered ----
  float4v xr;
  const int sr = tid >> 6, sm = tid & 63;          // src row, float4 idx
  const int stt = sm >> 1, sch = (sm & 1) * 4;     // dest tt, channel
  auto stage_load = [&](int chunk) {
    const float* src = x + ((size_t)bBase + sr) * (T_LEN * 8) +
                       (size_t)chunk * (TS * 8);
    xr = *(const float4v*)&src[sm * 4];
  };
  auto stage_write = [&](int buf) {
    union { u64 u; u16 s[4]; } p;
    p.s[0] = f2bf(xr[0]); p.s[1] = f2bf(xr[1]);
    p.s[2] = f2bf(xr[2]); p.s[3] = f2bf(xr[3]);
    *(u64*)&x_lds[buf][stt][sr][sch] = p.u;
  };

  stage_load(0);
  stage_write(0);
  __syncthreads();

  // hoisted select masks for the cndmask tree
  const bool sel1 = (rsel & 1) != 0;
  const bool sel2 = (rsel & 2) != 0;
  float c = 0.f;

  for (int ch = 0; ch < T_LEN / TS; ++ch) {
    const int xb = ch & 1;
    const bool more = (ch < T_LEN / TS - 1);
    for (int tt = 0; tt < TS; ++tt) {
      const int t = ch * TS + tt;
      const int hb = t & 1;
      if (tt == 0 && more) stage_load(ch + 1);  // reg loads; drain in stage_write

      // ---- B fragments (uniform b128 reads) ----
      const short8v fx  = *(const short8v*)&x_lds[xb][tt][row][8 * g4];
      const short8v fh0 = *(const short8v*)&h_lds[hb][row][8 * g4];
      const short8v fh1 = *(const short8v*)&h_lds[hb][row][32 + 8 * g4];

      // ---- 12 MFMAs: 4 gate-quads x (x | h-lo | h-hi) ----
      float4v acc[4];
#pragma unroll
      for (int g = 0; g < 4; ++g)
        acc[g] = __builtin_amdgcn_mfma_f32_16x16x32_bf16(
            a0[g], fx, (float4v){0.f, 0.f, 0.f, 0.f}, 0, 0, 0);
#pragma unroll
      for (int g = 0; g < 4; ++g)
        acc[g] = __builtin_amdgcn_mfma_f32_16x16x32_bf16(a1[g], fh0, acc[g], 0, 0, 0);
#pragma unroll
      for (int g = 0; g < 4; ++g)
        acc[g] = __builtin_amdgcn_mfma_f32_16x16x32_bf16(a2[g], fh1, acc[g], 0, 0, 0);

      // ---- pick this thread's element (reg-select tree) and activate ----
      float gsel[4];
#pragma unroll
      for (int g = 0; g < 4; ++g) {
        const float x01 = sel1 ? acc[g][1] : acc[g][0];
        const float x23 = sel1 ? acc[g][3] : acc[g][2];
        gsel[g] = sel2 ? x23 : x01;
      }
      const float iv = fsig(gsel[0]);
      const float fv = fsig(gsel[1]);
      const float gv = ftanh(gsel[2]);
      const float ov = fsig(gsel[3]);
      c = fv * c + iv * gv;
      const float h = ov * ftanh(c);
      h_lds[hb ^ 1][row][jh] = f2bf(h);
      if (t == T_LEN - 1) hf[row][jh] = h;
      if (tt == TS - 1 && more) stage_write((ch + 1) & 1);
      __syncthreads();  // one barrier per step
    }
  }

  // ---- epilogue: out[b] = sigmoid(hT . fc_w + fc_b) ----
  if (tid < R) {
    float a = fc_b[0];
#pragma unroll
    for (int k = 0; k < 64; ++k) a += hf[tid][k] * fc_w[k];
    out[bBase + tid] = fsig(a);
  }
}
}  // namespace

extern "C" void kernel_launch(void* const* d_in, const int* in_sizes, int n_in,
                              void* d_out, int out_size, void* d_ws,
                              size_t ws_size, hipStream_t stream) {
  const float* x    = (const float*)d_in[0];
  const float* W_ih = (const float*)d_in[1];
  const float* W_hh = (const float*)d_in[2];
  const float* b_ih = (const float*)d_in[3];
  const float* b_hh = (const float*)d_in[4];
  const float* fc_w = (const float*)d_in[5];
  const float* fc_b = (const float*)d_in[6];
  float* out = (float*)d_out;

  const int B = in_sizes[0] / (T_LEN * 8);  // 2048
  lstm_split<<<dim3(B / R), dim3(256), 0, stream>>>(x, W_ih, W_hh, b_ih, b_hh,
                                                    fc_w, fc_b, out);
}